// Round 9
// baseline (478.856 us; speedup 1.0000x reference)
//
#include <hip/hip_runtime.h>
#include <hip/hip_bf16.h>

// Problem constants (B=16, S=2048, D=240, E=8, TOP_K=2)
#define TOKENS 32768
#define Dm 240
#define NE 8
#define BK 32
#define NCHUNK 8      // K padded to 256 = 8 * 32
#define TILE_M 128    // R9: 64 -> 128 (2x MFMA per staging barrier)
#define GT_TOK 256    // R9: 128 -> 256 (halves gate atomic wall: 128 blocks)

typedef __bf16 bf16x8 __attribute__((ext_vector_type(8)));
typedef float  f32x4  __attribute__((ext_vector_type(4)));

__device__ __forceinline__ float b2f(unsigned short u) {
    union { unsigned int i; float f; } v; v.i = ((unsigned int)u) << 16; return v.f;
}
__device__ __forceinline__ unsigned short f2b(float f) {
    unsigned int i = __builtin_bit_cast(unsigned int, f);
    unsigned int r = (i + 0x7FFFu + ((i >> 16) & 1u)) >> 16;   // RNE
    return (unsigned short)r;
}
__device__ __forceinline__ unsigned short f2h(float f) {
    _Float16 h = (_Float16)f;
    union { _Float16 h; unsigned short u; } v; v.h = h; return v.u;
}
__device__ __forceinline__ float h2f(unsigned short u) {
    union { _Float16 h; unsigned short u; } v; v.u = u; return (float)v.h;
}
__device__ __forceinline__ uint4 pack8(float4 a, float4 b) {
    union { unsigned short u[8]; uint4 v; } r;
    r.u[0] = f2b(a.x); r.u[1] = f2b(a.y); r.u[2] = f2b(a.z); r.u[3] = f2b(a.w);
    r.u[4] = f2b(b.x); r.u[5] = f2b(b.y); r.u[6] = f2b(b.z); r.u[7] = f2b(b.w);
    return r.v;
}

// Classify input dtype on-device: fp32 data read as ushorts has ~25% of low
// halves with huge bf16 exponent (>= 2^65); bf16 N(0,1) data has none.
__global__ void detect_kernel(const unsigned short* __restrict__ x, int* flag) {
    int lane = threadIdx.x;   // 64 threads
    int hits = 0;
    for (int i = lane; i < 2048; i += 64) {
        unsigned e = (x[i] >> 7) & 0xFFu;
        if (e >= 0xC0u) hits++;
    }
    #pragma unroll
    for (int off = 32; off >= 1; off >>= 1) hits += __shfl_xor(hits, off, 64);
    if (lane == 0) flag[0] = (hits > 8) ? 1 : 0;
}

__global__ void init_kernel(int* cnt) {
    if (threadIdx.x < 16) cnt[threadIdx.x] = 0;
}

__global__ void zero_kernel(void* outv, const int* flag, int nelem) {
    long i = (long)blockIdx.x * blockDim.x + threadIdx.x;
    long stride = (long)gridDim.x * blockDim.x;
    if (*flag) {
        float* o = (float*)outv;
        for (; i < nelem; i += stride) o[i] = 0.f;
    } else {
        unsigned* o = (unsigned*)outv;          // 2 bf16 per word
        long n = nelem >> 1;
        for (; i < n; i += stride) o[i] = 0u;
    }
}

// ---------------------------------------------------------------------------
// Block-aggregated gate (R8-proven). 128 blocks x 256 tokens. Per-wave loop
// runs the proven gating math; routes in LDS; per-block histogram; 16 global
// atomics/block on UNCHANGED cnt layout (ws+64, stride 1); LDS-cursor scatter
// into UNCHANGED rt (ws+128, cap guard).
// ---------------------------------------------------------------------------
template<bool FP32>
__global__ __launch_bounds__(256) void gate_kernel(
    const void* __restrict__ xv, const void* __restrict__ gwv,
    const void* __restrict__ gbv, const int* __restrict__ flag,
    int* __restrict__ cnt, unsigned* __restrict__ rt, int cap)
{
    if ((*flag != 0) != FP32) return;
    __shared__ unsigned rv[GT_TOK];
    __shared__ int h[16];
    __shared__ int base[16];

    int tid  = threadIdx.x;
    int lane = tid & 63;
    int wave = tid >> 6;
    if (tid < 16) h[tid] = 0;

    int t0 = blockIdx.x * GT_TOK;
    for (int j = 0; j < GT_TOK / 4; j++) {       // 64 tokens per wave
        int sl = wave * (GT_TOK / 4) + j;
        int t  = t0 + sl;

        float xv0 = 0.f, xv1 = 0.f, xv2 = 0.f, xv3 = 0.f;
        if (lane < 60) {
            if (FP32) {
                float4 u = *(const float4*)&((const float*)xv)[t * Dm + lane * 4];
                xv0 = u.x; xv1 = u.y; xv2 = u.z; xv3 = u.w;
            } else {
                ushort4 u = *(const ushort4*)&((const unsigned short*)xv)[t * Dm + lane * 4];
                xv0 = b2f(u.x); xv1 = b2f(u.y); xv2 = b2f(u.z); xv3 = b2f(u.w);
            }
        }
        float logit[NE];
        #pragma unroll
        for (int e = 0; e < NE; e++) {
            float p = 0.f;
            if (lane < 60) {
                if (FP32) {
                    float4 g = *(const float4*)&((const float*)gwv)[e * Dm + lane * 4];
                    p = xv0 * g.x + xv1 * g.y + xv2 * g.z + xv3 * g.w;
                } else {
                    ushort4 g = *(const ushort4*)&((const unsigned short*)gwv)[e * Dm + lane * 4];
                    p = xv0 * b2f(g.x) + xv1 * b2f(g.y) + xv2 * b2f(g.z) + xv3 * b2f(g.w);
                }
            }
            #pragma unroll
            for (int off = 32; off >= 1; off >>= 1) p += __shfl_xor(p, off, 64);
            float bias = FP32 ? ((const float*)gbv)[e] : b2f(((const unsigned short*)gbv)[e]);
            logit[e] = p + bias;
        }
        // top-2 (strict > keeps lowest index on ties, matching lax.top_k)
        float l0 = -1e30f; int e0 = 0;
        #pragma unroll
        for (int e = 0; e < NE; e++) if (logit[e] > l0) { l0 = logit[e]; e0 = e; }
        float l1 = -1e30f; int e1 = 0;
        #pragma unroll
        for (int e = 0; e < NE; e++) if (e != e0 && logit[e] > l1) { l1 = logit[e]; e1 = e; }
        float w0 = 1.f / (1.f + __expf(l1 - l0));    // renormalized top-2 softmax

        if (lane == 0)
            rv[sl] = ((unsigned)e1 << 20) | ((unsigned)e0 << 16) | (unsigned)f2h(w0);
    }
    __syncthreads();

    if (tid < GT_TOK) {                          // per-block histogram
        unsigned v = rv[tid];
        atomicAdd(&h[(v >> 16) & 7], 1);
        atomicAdd(&h[8 + ((v >> 20) & 7)], 1);
    }
    __syncthreads();

    if (tid < 16) {                              // 16 global atomics per block
        base[tid] = atomicAdd(&cnt[tid], h[tid]);
        h[tid] = 0;
    }
    __syncthreads();

    if (tid < GT_TOK) {                          // LDS-cursor scatter
        unsigned v = rv[tid];
        int t  = t0 + tid;
        int e0 = (v >> 16) & 7;
        int e1 = (v >> 20) & 7;
        unsigned short hw0 = (unsigned short)(v & 0xFFFFu);
        int o0 = atomicAdd(&h[e0], 1);
        int p0 = base[e0] + o0;
        if (p0 < cap) rt[e0 * cap + p0] = ((unsigned)t << 16) | hw0;
        int o1 = atomicAdd(&h[8 + e1], 1);
        int p1 = base[8 + e1] + o1;
        if (p1 < cap) rt[(8 + e1) * cap + p1] = ((unsigned)t << 16) | (unsigned)f2h(1.f - h2f(hw0));
    }
}

// Block = (tile, expert), tile = 128 tokens. Double-buffered LDS staging,
// 16x16x32 bf16 MFMA, 8x4 acc tiles per wave (128x256 out per block).
template<bool FP32>
__global__ __launch_bounds__(256) void expert_kernel(
    const void* __restrict__ xv, const void* __restrict__ ewv,
    const void* __restrict__ ebv, const int* __restrict__ flag,
    const int* __restrict__ cnt, const unsigned* __restrict__ rt, int cap,
    void* __restrict__ outv, int slotBase, int accumulate)
{
    if ((*flag != 0) != FP32) return;
    int e = blockIdx.y;
    int tile = blockIdx.x;
    int bucket = slotBase + e;
    int ne = min(cnt[bucket], cap);
    int m0 = tile * TILE_M;
    if (m0 >= ne) return;
    int rows = min(TILE_M, ne - m0);

    // +8 bf16 row pad -> row stride 80B -> only 2-way bank aliasing (free)
    __shared__ __align__(16) unsigned short Wc[2][256][40];
    __shared__ __align__(16) unsigned short Xc[2][TILE_M][40];
    __shared__ int   tokS[TILE_M];
    __shared__ float twS[TILE_M];

    int tid = threadIdx.x;
    if (tid < TILE_M) {
        int i = min(m0 + tid, ne - 1);      // clamp: padded rows gather a valid row
        unsigned v = rt[bucket * cap + i];
        tokS[tid] = (int)(v >> 16);
        twS[tid]  = (tid < rows) ? h2f((unsigned short)(v & 0xFFFFu)) : 0.f;
    }
    __syncthreads();

    int srow = tid >> 2;      // 0..63
    int part = tid & 3;       // 4 x 8 elements per 32-elem row chunk

    auto stage = [&](int c, int buf) {
        int kk = c * BK + part * 8;                 // element offset
        bool kvalid = (kk < Dm);                    // 240 % 8 == 0
        if (FP32) {
            const float* xf = (const float*)xv;
            const float* Wf = (const float*)ewv + e * Dm * Dm;
            #pragma unroll
            for (int it = 0; it < TILE_M / 64; it++) {
                int r = srow + it * 64;
                uint4 xq = make_uint4(0, 0, 0, 0);
                if (kvalid) {
                    const float* s = &xf[(long)tokS[r] * Dm + kk];
                    xq = pack8(*(const float4*)s, *(const float4*)(s + 4));
                }
                *(uint4*)&Xc[buf][r][part * 8] = xq;
            }
            #pragma unroll
            for (int it = 0; it < 4; it++) {
                int n = srow + it * 64;
                uint4 wq = make_uint4(0, 0, 0, 0);
                if (kvalid && n < Dm) {
                    const float* s = &Wf[(long)n * Dm + kk];
                    wq = pack8(*(const float4*)s, *(const float4*)(s + 4));
                }
                *(uint4*)&Wc[buf][n][part * 8] = wq;
            }
        } else {
            const unsigned short* xb = (const unsigned short*)xv;
            const unsigned short* Wb = (const unsigned short*)ewv + e * Dm * Dm;
            #pragma unroll
            for (int it = 0; it < TILE_M / 64; it++) {
                int r = srow + it * 64;
                uint4 xq = make_uint4(0, 0, 0, 0);
                if (kvalid) xq = *(const uint4*)&xb[(long)tokS[r] * Dm + kk];
                *(uint4*)&Xc[buf][r][part * 8] = xq;
            }
            #pragma unroll
            for (int it = 0; it < 4; it++) {
                int n = srow + it * 64;
                uint4 wq = make_uint4(0, 0, 0, 0);
                if (kvalid && n < Dm) wq = *(const uint4*)&Wb[(long)n * Dm + kk];
                *(uint4*)&Wc[buf][n][part * 8] = wq;
            }
        }
    };

    int lane = tid & 63;
    int wv   = tid >> 6;                  // wave id: owns n in [64*wv, 64*wv+64)
    int frow = lane & 15;
    int koff = (lane >> 4) * 8;

    f32x4 acc[TILE_M / 16][4] = {};

    stage(0, 0);
    __syncthreads();
    for (int c = 0; c < NCHUNK; c++) {
        int buf = c & 1;
        bf16x8 a[TILE_M / 16], b[4];
        #pragma unroll
        for (int mt = 0; mt < TILE_M / 16; mt++)
            a[mt] = *(const bf16x8*)&Xc[buf][mt * 16 + frow][koff];
        #pragma unroll
        for (int nt = 0; nt < 4; nt++)
            b[nt] = *(const bf16x8*)&Wc[buf][wv * 64 + nt * 16 + frow][koff];
        if (c + 1 < NCHUNK) stage(c + 1, (c + 1) & 1);
        #pragma unroll
        for (int mt = 0; mt < TILE_M / 16; mt++)
            #pragma unroll
            for (int nt = 0; nt < 4; nt++)
                acc[mt][nt] = __builtin_amdgcn_mfma_f32_16x16x32_bf16(
                    a[mt], b[nt], acc[mt][nt], 0, 0, 0);
        __syncthreads();
    }

    // Epilogue: C/D layout col=lane&15, row=(lane>>4)*4+r  [guide §3, m89-verified]
    int colg  = lane & 15;
    int rquad = (lane >> 4) * 4;
    #pragma unroll
    for (int nt = 0; nt < 4; nt++) {
        int n = wv * 64 + nt * 16 + colg;
        if (n >= Dm) continue;                      // N padded 240->256
        float bn = FP32 ? ((const float*)ebv)[e * Dm + n]
                        : b2f(((const unsigned short*)ebv)[e * Dm + n]);
        #pragma unroll
        for (int mt = 0; mt < TILE_M / 16; mt++) {
            #pragma unroll
            for (int r = 0; r < 4; r++) {
                int m = mt * 16 + rquad + r;
                if (m < rows) {
                    float val = (acc[mt][nt][r] + bn) * twS[m];
                    long idx = (long)tokS[m] * Dm + n;
                    if (FP32) {
                        float* o = (float*)outv + idx;
                        *o = accumulate ? (*o + val) : val;
                    } else {
                        unsigned short* o = (unsigned short*)outv + idx;
                        *o = accumulate ? f2b(b2f(*o) + val) : f2b(val);
                    }
                }
            }
        }
    }
}

extern "C" void kernel_launch(void* const* d_in, const int* in_sizes, int n_in,
                              void* d_out, int out_size, void* d_ws, size_t ws_size,
                              hipStream_t stream) {
    const void* x  = d_in[0];
    const void* gw = d_in[1];
    const void* gb = d_in[2];
    const void* ew = d_in[3];
    const void* eb = d_in[4];

    char* ws = (char*)d_ws;
    int* flag = (int*)ws;                 // [0]   dtype flag
    int* cnt  = (int*)(ws + 64);          // [16]  bucket counters
    unsigned* rt = (unsigned*)(ws + 128); // [16][cap] packed (token<<16 | fp16 w)

    long capl = ((long)ws_size - 128) / (16 * sizeof(unsigned));
    if (capl > TOKENS) capl = TOKENS;
    if (capl < 64) capl = 64;
    int cap = (int)capl;
    int tiles = (cap + TILE_M - 1) / TILE_M;
    bool lossless = (cap >= TOKENS);
    int acc0 = lossless ? 0 : 1;

    detect_kernel<<<1, 64, 0, stream>>>((const unsigned short*)x, flag);
    init_kernel<<<1, 64, 0, stream>>>(cnt);
    gate_kernel<false><<<TOKENS / GT_TOK, 256, 0, stream>>>(x, gw, gb, flag, cnt, rt, cap);
    gate_kernel<true ><<<TOKENS / GT_TOK, 256, 0, stream>>>(x, gw, gb, flag, cnt, rt, cap);
    if (!lossless)
        zero_kernel<<<1024, 256, 0, stream>>>(d_out, flag, out_size);
    expert_kernel<false><<<dim3(tiles, NE), 256, 0, stream>>>(x, ew, eb, flag, cnt, rt, cap, d_out, 0, acc0);
    expert_kernel<true ><<<dim3(tiles, NE), 256, 0, stream>>>(x, ew, eb, flag, cnt, rt, cap, d_out, 0, acc0);
    expert_kernel<false><<<dim3(tiles, NE), 256, 0, stream>>>(x, ew, eb, flag, cnt, rt, cap, d_out, 8, 1);
    expert_kernel<true ><<<dim3(tiles, NE), 256, 0, stream>>>(x, ew, eb, flag, cnt, rt, cap, d_out, 8, 1);
}

// Round 10
// 197.338 us; speedup vs baseline: 2.4266x; 2.4266x over previous
//
#include <hip/hip_runtime.h>
#include <hip/hip_bf16.h>

// Problem constants (B=16, S=2048, D=240, E=8, TOP_K=2)
#define TOKENS 32768
#define Dm 240
#define NE 8
#define BK 32
#define NCHUNK 8      // K padded to 256 = 8 * 32
#define TILE_M 64     // R10: reverted to R8-proven (128 cost occupancy, -2x)

typedef __bf16 bf16x8 __attribute__((ext_vector_type(8)));
typedef float  f32x4  __attribute__((ext_vector_type(4)));

__device__ __forceinline__ float b2f(unsigned short u) {
    union { unsigned int i; float f; } v; v.i = ((unsigned int)u) << 16; return v.f;
}
__device__ __forceinline__ float b2f_lo(unsigned u) {      // low bf16 of a word
    union { unsigned int i; float f; } v; v.i = u << 16; return v.f;
}
__device__ __forceinline__ float b2f_hi(unsigned u) {      // high bf16 of a word
    union { unsigned int i; float f; } v; v.i = u & 0xFFFF0000u; return v.f;
}
__device__ __forceinline__ unsigned short f2b(float f) {
    unsigned int i = __builtin_bit_cast(unsigned int, f);
    unsigned int r = (i + 0x7FFFu + ((i >> 16) & 1u)) >> 16;   // RNE
    return (unsigned short)r;
}
__device__ __forceinline__ unsigned short f2h(float f) {
    _Float16 h = (_Float16)f;
    union { _Float16 h; unsigned short u; } v; v.h = h; return v.u;
}
__device__ __forceinline__ float h2f(unsigned short u) {
    union { _Float16 h; unsigned short u; } v; v.u = u; return (float)v.h;
}
__device__ __forceinline__ uint4 pack8(float4 a, float4 b) {
    union { unsigned short u[8]; uint4 v; } r;
    r.u[0] = f2b(a.x); r.u[1] = f2b(a.y); r.u[2] = f2b(a.z); r.u[3] = f2b(a.w);
    r.u[4] = f2b(b.x); r.u[5] = f2b(b.y); r.u[6] = f2b(b.z); r.u[7] = f2b(b.w);
    return r.v;
}

// Classify input dtype on-device: fp32 data read as ushorts has ~25% of low
// halves with huge bf16 exponent (>= 2^65); bf16 N(0,1) data has none.
__global__ void detect_kernel(const unsigned short* __restrict__ x, int* flag) {
    int lane = threadIdx.x;   // 64 threads
    int hits = 0;
    for (int i = lane; i < 2048; i += 64) {
        unsigned e = (x[i] >> 7) & 0xFFu;
        if (e >= 0xC0u) hits++;
    }
    #pragma unroll
    for (int off = 32; off >= 1; off >>= 1) hits += __shfl_xor(hits, off, 64);
    if (lane == 0) flag[0] = (hits > 8) ? 1 : 0;
}

__global__ void init_kernel(int* cnt) {
    if (threadIdx.x < 16) cnt[threadIdx.x] = 0;
}

__global__ void zero_kernel(void* outv, const int* flag, int nelem) {
    long i = (long)blockIdx.x * blockDim.x + threadIdx.x;
    long stride = (long)gridDim.x * blockDim.x;
    if (*flag) {
        float* o = (float*)outv;
        for (; i < nelem; i += stride) o[i] = 0.f;
    } else {
        unsigned* o = (unsigned*)outv;          // 2 bf16 per word
        long n = nelem >> 1;
        for (; i < n; i += stride) o[i] = 0u;
    }
}

// ---------------------------------------------------------------------------
// ROUND-10 gate: ONE THREAD PER TOKEN (replaces wave-per-token shuffle chains
// -- R9 proved gate scales with serial per-block work, not atomics).
// 128 blocks x 256 threads; each thread streams its own x row (30 x uint4,
// deep vmcnt pipeline) and FMAs against uniform-loaded gate weights.
// Aggregation (LDS hist -> 16 global atomics/block -> LDS-cursor scatter)
// is byte-identical to the R8/R9-proven idiom.
// ---------------------------------------------------------------------------
template<bool FP32>
__global__ __launch_bounds__(256) void gate_kernel(
    const void* __restrict__ xv, const void* __restrict__ gwv,
    const void* __restrict__ gbv, const int* __restrict__ flag,
    int* __restrict__ cnt, unsigned* __restrict__ rt, int cap)
{
    if ((*flag != 0) != FP32) return;
    __shared__ unsigned rv[256];
    __shared__ int h[16];
    __shared__ int base[16];

    int tid = threadIdx.x;
    if (tid < 16) h[tid] = 0;
    int t = blockIdx.x * 256 + tid;

    float acc[NE];
    #pragma unroll
    for (int e = 0; e < NE; e++)
        acc[e] = FP32 ? ((const float*)gbv)[e]
                      : b2f(((const unsigned short*)gbv)[e]);

    if (FP32) {
        const float* xf  = (const float*)xv + (long)t * Dm;
        const float* gwf = (const float*)gwv;
        for (int k = 0; k < Dm; k += 8) {
            float4 xa = *(const float4*)&xf[k];
            float4 xb = *(const float4*)&xf[k + 4];
            #pragma unroll
            for (int e = 0; e < NE; e++) {
                float4 ga = *(const float4*)&gwf[e * Dm + k];      // uniform
                float4 gb = *(const float4*)&gwf[e * Dm + k + 4];  // uniform
                acc[e] += xa.x * ga.x + xa.y * ga.y + xa.z * ga.z + xa.w * ga.w
                        + xb.x * gb.x + xb.y * gb.y + xb.z * gb.z + xb.w * gb.w;
            }
        }
    } else {
        const unsigned short* xb  = (const unsigned short*)xv + (long)t * Dm;
        const unsigned short* gwb = (const unsigned short*)gwv;
        for (int k = 0; k < Dm; k += 8) {
            uint4 xq = *(const uint4*)&xb[k];
            float x0 = b2f_lo(xq.x), x1 = b2f_hi(xq.x);
            float x2 = b2f_lo(xq.y), x3 = b2f_hi(xq.y);
            float x4 = b2f_lo(xq.z), x5 = b2f_hi(xq.z);
            float x6 = b2f_lo(xq.w), x7 = b2f_hi(xq.w);
            #pragma unroll
            for (int e = 0; e < NE; e++) {
                uint4 gq = *(const uint4*)&gwb[e * Dm + k];        // uniform
                acc[e] += x0 * b2f_lo(gq.x) + x1 * b2f_hi(gq.x)
                        + x2 * b2f_lo(gq.y) + x3 * b2f_hi(gq.y)
                        + x4 * b2f_lo(gq.z) + x5 * b2f_hi(gq.z)
                        + x6 * b2f_lo(gq.w) + x7 * b2f_hi(gq.w);
            }
        }
    }

    // top-2 (strict > keeps lowest index on ties, matching lax.top_k)
    float l0 = -1e30f; int e0 = 0;
    #pragma unroll
    for (int e = 0; e < NE; e++) if (acc[e] > l0) { l0 = acc[e]; e0 = e; }
    float l1 = -1e30f; int e1 = 0;
    #pragma unroll
    for (int e = 0; e < NE; e++) if (e != e0 && acc[e] > l1) { l1 = acc[e]; e1 = e; }
    float w0 = 1.f / (1.f + __expf(l1 - l0));    // renormalized top-2 softmax

    rv[tid] = ((unsigned)e1 << 20) | ((unsigned)e0 << 16) | (unsigned)f2h(w0);
    __syncthreads();

    {   // per-block histogram (R8-proven idiom)
        unsigned v = rv[tid];
        atomicAdd(&h[(v >> 16) & 7], 1);
        atomicAdd(&h[8 + ((v >> 20) & 7)], 1);
    }
    __syncthreads();

    if (tid < 16) {                              // 16 global atomics per block
        base[tid] = atomicAdd(&cnt[tid], h[tid]);
        h[tid] = 0;
    }
    __syncthreads();

    {   // LDS-cursor scatter (R8-proven idiom)
        unsigned v = rv[tid];
        int tt = blockIdx.x * 256 + tid;
        int a0 = (v >> 16) & 7;
        int a1 = (v >> 20) & 7;
        unsigned short hw0 = (unsigned short)(v & 0xFFFFu);
        int o0 = atomicAdd(&h[a0], 1);
        int p0 = base[a0] + o0;
        if (p0 < cap) rt[a0 * cap + p0] = ((unsigned)tt << 16) | hw0;
        int o1 = atomicAdd(&h[8 + a1], 1);
        int p1 = base[8 + a1] + o1;
        if (p1 < cap) rt[(8 + a1) * cap + p1] = ((unsigned)tt << 16) | (unsigned)f2h(1.f - h2f(hw0));
    }
}

// Block = (tile, expert), tile = 64 tokens (R8-proven). Double-buffered LDS
// staging, 16x16x32 bf16 MFMA, 4x4 acc tiles per wave.
template<bool FP32>
__global__ __launch_bounds__(256) void expert_kernel(
    const void* __restrict__ xv, const void* __restrict__ ewv,
    const void* __restrict__ ebv, const int* __restrict__ flag,
    const int* __restrict__ cnt, const unsigned* __restrict__ rt, int cap,
    void* __restrict__ outv, int slotBase, int accumulate)
{
    if ((*flag != 0) != FP32) return;
    int e = blockIdx.y;
    int tile = blockIdx.x;
    int bucket = slotBase + e;
    int ne = min(cnt[bucket], cap);
    int m0 = tile * TILE_M;
    if (m0 >= ne) return;
    int rows = min(TILE_M, ne - m0);

    // +8 bf16 row pad -> row stride 80B -> only 2-way bank aliasing (free)
    __shared__ __align__(16) unsigned short Wc[2][256][40];
    __shared__ __align__(16) unsigned short Xc[2][TILE_M][40];
    __shared__ int   tokS[TILE_M];
    __shared__ float twS[TILE_M];

    int tid = threadIdx.x;
    if (tid < TILE_M) {
        int i = min(m0 + tid, ne - 1);      // clamp: padded rows gather a valid row
        unsigned v = rt[bucket * cap + i];
        tokS[tid] = (int)(v >> 16);
        twS[tid]  = (tid < rows) ? h2f((unsigned short)(v & 0xFFFFu)) : 0.f;
    }
    __syncthreads();

    int srow = tid >> 2;      // 0..63
    int part = tid & 3;       // 4 x 8 elements per 32-elem row chunk

    auto stage = [&](int c, int buf) {
        int kk = c * BK + part * 8;                 // element offset
        bool kvalid = (kk < Dm);                    // 240 % 8 == 0
        if (FP32) {
            const float* xf = (const float*)xv;
            const float* Wf = (const float*)ewv + e * Dm * Dm;
            uint4 xq = make_uint4(0, 0, 0, 0);
            if (kvalid) {
                const float* s = &xf[(long)tokS[srow] * Dm + kk];
                xq = pack8(*(const float4*)s, *(const float4*)(s + 4));
            }
            *(uint4*)&Xc[buf][srow][part * 8] = xq;
            #pragma unroll
            for (int it = 0; it < 4; it++) {
                int n = srow + it * 64;
                uint4 wq = make_uint4(0, 0, 0, 0);
                if (kvalid && n < Dm) {
                    const float* s = &Wf[(long)n * Dm + kk];
                    wq = pack8(*(const float4*)s, *(const float4*)(s + 4));
                }
                *(uint4*)&Wc[buf][n][part * 8] = wq;
            }
        } else {
            const unsigned short* xb = (const unsigned short*)xv;
            const unsigned short* Wb = (const unsigned short*)ewv + e * Dm * Dm;
            uint4 xq = make_uint4(0, 0, 0, 0);
            if (kvalid) xq = *(const uint4*)&xb[(long)tokS[srow] * Dm + kk];
            *(uint4*)&Xc[buf][srow][part * 8] = xq;
            #pragma unroll
            for (int it = 0; it < 4; it++) {
                int n = srow + it * 64;
                uint4 wq = make_uint4(0, 0, 0, 0);
                if (kvalid && n < Dm) wq = *(const uint4*)&Wb[(long)n * Dm + kk];
                *(uint4*)&Wc[buf][n][part * 8] = wq;
            }
        }
    };

    int lane = tid & 63;
    int wv   = tid >> 6;                  // wave id: owns n in [64*wv, 64*wv+64)
    int frow = lane & 15;
    int koff = (lane >> 4) * 8;

    f32x4 acc[TILE_M / 16][4] = {};

    stage(0, 0);
    __syncthreads();
    for (int c = 0; c < NCHUNK; c++) {
        int buf = c & 1;
        bf16x8 a[TILE_M / 16], b[4];
        #pragma unroll
        for (int mt = 0; mt < TILE_M / 16; mt++)
            a[mt] = *(const bf16x8*)&Xc[buf][mt * 16 + frow][koff];
        #pragma unroll
        for (int nt = 0; nt < 4; nt++)
            b[nt] = *(const bf16x8*)&Wc[buf][wv * 64 + nt * 16 + frow][koff];
        if (c + 1 < NCHUNK) stage(c + 1, (c + 1) & 1);
        #pragma unroll
        for (int mt = 0; mt < TILE_M / 16; mt++)
            #pragma unroll
            for (int nt = 0; nt < 4; nt++)
                acc[mt][nt] = __builtin_amdgcn_mfma_f32_16x16x32_bf16(
                    a[mt], b[nt], acc[mt][nt], 0, 0, 0);
        __syncthreads();
    }

    // Epilogue: C/D layout col=lane&15, row=(lane>>4)*4+r  [guide §3, m89-verified]
    int colg  = lane & 15;
    int rquad = (lane >> 4) * 4;
    #pragma unroll
    for (int nt = 0; nt < 4; nt++) {
        int n = wv * 64 + nt * 16 + colg;
        if (n >= Dm) continue;                      // N padded 240->256
        float bn = FP32 ? ((const float*)ebv)[e * Dm + n]
                        : b2f(((const unsigned short*)ebv)[e * Dm + n]);
        #pragma unroll
        for (int mt = 0; mt < TILE_M / 16; mt++) {
            #pragma unroll
            for (int r = 0; r < 4; r++) {
                int m = mt * 16 + rquad + r;
                if (m < rows) {
                    float val = (acc[mt][nt][r] + bn) * twS[m];
                    long idx = (long)tokS[m] * Dm + n;
                    if (FP32) {
                        float* o = (float*)outv + idx;
                        *o = accumulate ? (*o + val) : val;
                    } else {
                        unsigned short* o = (unsigned short*)outv + idx;
                        *o = accumulate ? f2b(b2f(*o) + val) : f2b(val);
                    }
                }
            }
        }
    }
}

extern "C" void kernel_launch(void* const* d_in, const int* in_sizes, int n_in,
                              void* d_out, int out_size, void* d_ws, size_t ws_size,
                              hipStream_t stream) {
    const void* x  = d_in[0];
    const void* gw = d_in[1];
    const void* gb = d_in[2];
    const void* ew = d_in[3];
    const void* eb = d_in[4];

    char* ws = (char*)d_ws;
    int* flag = (int*)ws;                 // [0]   dtype flag
    int* cnt  = (int*)(ws + 64);          // [16]  bucket counters
    unsigned* rt = (unsigned*)(ws + 128); // [16][cap] packed (token<<16 | fp16 w)

    long capl = ((long)ws_size - 128) / (16 * sizeof(unsigned));
    if (capl > TOKENS) capl = TOKENS;
    if (capl < 64) capl = 64;
    int cap = (int)capl;
    int tiles = (cap + TILE_M - 1) / TILE_M;
    bool lossless = (cap >= TOKENS);
    int acc0 = lossless ? 0 : 1;

    detect_kernel<<<1, 64, 0, stream>>>((const unsigned short*)x, flag);
    init_kernel<<<1, 64, 0, stream>>>(cnt);
    gate_kernel<false><<<TOKENS / 256, 256, 0, stream>>>(x, gw, gb, flag, cnt, rt, cap);
    gate_kernel<true ><<<TOKENS / 256, 256, 0, stream>>>(x, gw, gb, flag, cnt, rt, cap);
    if (!lossless)
        zero_kernel<<<1024, 256, 0, stream>>>(d_out, flag, out_size);
    expert_kernel<false><<<dim3(tiles, NE), 256, 0, stream>>>(x, ew, eb, flag, cnt, rt, cap, d_out, 0, acc0);
    expert_kernel<true ><<<dim3(tiles, NE), 256, 0, stream>>>(x, ew, eb, flag, cnt, rt, cap, d_out, 0, acc0);
    expert_kernel<false><<<dim3(tiles, NE), 256, 0, stream>>>(x, ew, eb, flag, cnt, rt, cap, d_out, 8, 1);
    expert_kernel<true ><<<dim3(tiles, NE), 256, 0, stream>>>(x, ew, eb, flag, cnt, rt, cap, d_out, 8, 1);
}